// Round 3
// baseline (817.560 us; speedup 1.0000x reference)
//
#include <hip/hip_runtime.h>
#include <stdint.h>
#include <type_traits>

// Problem constants
#define BB  4
#define SS  2048
#define DD  1024
#define HH  16
#define HDD 64

typedef __attribute__((ext_vector_type(8))) short s16x8;   // 8 bf16 (4 VGPRs)
typedef __attribute__((ext_vector_type(4))) float f32x4;   // MFMA C/D

__device__ inline short f2bf(float f) {
    union { float f; unsigned int u; } v; v.f = f;
    unsigned int r = (v.u + 0x7fffu + ((v.u >> 16) & 1u)) >> 16; // RNE
    return (short)r;
}

#define GLL(gp, lp) __builtin_amdgcn_global_load_lds( \
    (const __attribute__((address_space(1))) void*)(gp), \
    (__attribute__((address_space(3))) void*)(lp), 16, 0, 0)

// Raw barrier that does NOT drain vmcnt (prefetch loads stay in flight).
// lgkmcnt(0) orders this wave's LDS ops; sched_barrier pins (rule #18).
__device__ inline void lds_barrier() {
    asm volatile("s_waitcnt lgkmcnt(0)" ::: "memory");
    __builtin_amdgcn_sched_barrier(0);
    __builtin_amdgcn_s_barrier();
}

// ---------------- fp32 -> bf16 cast (n % 8 == 0) ----------------
__global__ void cvt_kernel(const float* __restrict__ src, short* __restrict__ dst, int n) {
    int i = (blockIdx.x * 256 + threadIdx.x) * 8;
    if (i >= n) return;
    const float4* s = (const float4*)(src + i);
    float4 a = s[0], b = s[1];
    s16x8 o;
    o[0]=f2bf(a.x); o[1]=f2bf(a.y); o[2]=f2bf(a.z); o[3]=f2bf(a.w);
    o[4]=f2bf(b.x); o[5]=f2bf(b.y); o[6]=f2bf(b.z); o[7]=f2bf(b.w);
    *(s16x8*)(dst + i) = o;
}

// ---------------- GEMM C = A @ B^T + bias (m97 structure) ----------------
template<int EPI>
__global__ __launch_bounds__(256)
void gemm_bt(const short* __restrict__ A, const short* __restrict__ Bw,
             const float* __restrict__ bias, float* __restrict__ Cf,
             short* __restrict__ Qo, short* __restrict__ Ko, short* __restrict__ Vo,
             int M, int N, int K)
{
    __shared__ short lsA[128 * 32];
    __shared__ short lsB[128 * 32];
    const int tid  = threadIdx.x;
    const int w    = tid >> 6, lane = tid & 63;
    const int quad = lane >> 4, l15 = lane & 15;
    const int m0 = blockIdx.x * 128, n0 = blockIdx.y * 128;
    const int mw = (w & 1) * 64, nw = (w >> 1) * 64;

    f32x4 acc[4][4] = {};

    const int srow = w * 32 + (lane >> 2);
    const int scol = (lane & 3) * 8;
    const short* pA = A + (size_t)(m0 + srow) * K + scol;
    const short* pB = Bw + (size_t)(n0 + srow) * K + scol;
    short* lAbase0 = &lsA[(w * 32) * 32];
    short* lAbase1 = &lsA[(w * 32 + 16) * 32];
    short* lBbase0 = &lsB[(w * 32) * 32];
    short* lBbase1 = &lsB[(w * 32 + 16) * 32];

    for (int kk = 0; kk < K; kk += 32) {
        __syncthreads();
        GLL(pA + kk,            lAbase0);
        GLL(pA + kk + 16 * K,   lAbase1);
        GLL(pB + kk,            lBbase0);
        GLL(pB + kk + 16 * K,   lBbase1);
        asm volatile("s_waitcnt vmcnt(0)" ::: "memory");
        __syncthreads();

        s16x8 af[4], bfr[4];
        for (int t = 0; t < 4; ++t) {
            af[t]  = *(const s16x8*)&lsA[(mw + t * 16 + l15) * 32 + quad * 8];
            bfr[t] = *(const s16x8*)&lsB[(nw + t * 16 + l15) * 32 + quad * 8];
        }
        for (int i = 0; i < 4; ++i)
            for (int j = 0; j < 4; ++j)
                acc[i][j] = __builtin_amdgcn_mfma_f32_16x16x32_bf16(af[i], bfr[j], acc[i][j], 0, 0, 0);
    }

    if (EPI == 0) {
        for (int i = 0; i < 4; ++i) {
            int row = m0 + mw + i * 16 + quad * 4;
            for (int j = 0; j < 4; ++j) {
                int col = n0 + nw + j * 16 + l15;
                float bv = bias[col];
                for (int r = 0; r < 4; ++r)
                    Cf[(size_t)(row + r) * N + col] = acc[i][j][r] + bv;
            }
        }
    } else {
        for (int i = 0; i < 4; ++i) {
            int row = m0 + mw + i * 16 + quad * 4;
            for (int j = 0; j < 4; ++j) {
                int col = n0 + nw + j * 16 + l15;
                float bv = bias[col];
                int sel = col >> 10, h = (col >> 6) & 15, hd = col & 63;
                for (int r = 0; r < 4; ++r) {
                    int rr = row + r;
                    int b = rr >> 11, s = rr & 2047;
                    short val = f2bf(acc[i][j][r] + bv);
                    if (sel == 0)      Qo[(((size_t)b * HH + h) * SS + s) * HDD + hd] = val;
                    else if (sel == 1) Ko[(((size_t)b * HH + h) * SS + s) * HDD + hd] = val;
                    else               Vo[(((size_t)b * HH + h) * HDD + hd) * SS + s] = val;
                }
            }
        }
    }
}

// ---------------- causal flash attention (LDS-staged + T14 async prefetch) ----------------
// Q,K: (b,h,s,hd) bf16; V: (b,h,hd,s) bf16; O: (b,s,h*64+hd) bf16
// grid: (16, B*H). Block t-loop handles q-tiles {31-bx, bx} (17 tile-units each).
// Per 128-key tile: ds_write K/V from PREFETCHED regs, issue next tile's global
// loads (stay in flight across raw barriers - no vmcnt drain!), QK^T from LDS,
// softmax, P->swizzled per-wave LDS (aliases lsK after lds_barrier), PV from LDS.
// Uniform NT=8 tiles: even-qb causal tail padded to 128 keys (upper 64 masked).
__global__ __launch_bounds__(256, 3)
void attn_kernel(const short* __restrict__ Q, const short* __restrict__ Kb,
                 const short* __restrict__ Vb, const int* __restrict__ mask,
                 short* __restrict__ O)
{
    __shared__ short lsK[128 * 72];        // [key][hd] pad 64->72; P aliases (per-wave 16x136 swizzled)
    __shared__ short lsV[64 * 136];        // [hd][key] pad 128->136

    const int tid  = threadIdx.x;
    const int w    = tid >> 6, lane = tid & 63;
    const int quad = lane >> 4, l15 = lane & 15;
    const int bx = blockIdx.x, bh = blockIdx.y;
    const int b = bh >> 4;
    const size_t baseQK = (size_t)bh * SS * HDD;
    const size_t baseV  = (size_t)bh * HDD * SS;
    short* lsPw = &lsK[w * 16 * 136];
    const float SC = 0.18033688f;          // (1/8) * log2(e)
    const int rsw = (l15 >> 3) << 4;       // P read-side XOR (short-index units)
    const int wsw = (quad >> 1) << 4;      // P write-side XOR: row=quad*4+r -> row>>3 == quad>>1

    for (int t = 0; t < 2; ++t) {
        const int qb = t ? bx : (31 - bx);  // heavy tile first
        const int q0 = qb * 64;
        const int qrow = q0 + w * 16 + l15;
        const int rowg0 = q0 + w * 16 + quad * 4;

        s16x8 aq[2];
        for (int ks = 0; ks < 2; ++ks)
            aq[ks] = *(const s16x8*)(Q + baseQK + (size_t)qrow * HDD + ks * 32 + quad * 8);

        float m_r[4], l_r[4];
        f32x4 o_acc[4] = {};
        for (int r = 0; r < 4; ++r) { m_r[r] = -1e30f; l_r[r] = 0.f; }

        // issue next tile's K/V global->reg loads (prefetch)
        auto issue = [&](int kv0, s16x8* kr, s16x8* vr) {
#pragma unroll
            for (int i = 0; i < 4; ++i) {
                int ch = tid + i * 256;
                kr[i] = *(const s16x8*)(Kb + baseQK + (size_t)(kv0 + (ch >> 3)) * HDD + (ch & 7) * 8);
            }
#pragma unroll
            for (int i = 0; i < 4; ++i) {
                int ch = tid + i * 256;
                vr[i] = *(const s16x8*)(Vb + baseV + (size_t)(ch >> 4) * SS + kv0 + (ch & 15) * 8);
            }
        };
        // write prefetched regs into LDS (vmcnt waits only here, loads long landed)
        auto stage_write = [&](const s16x8* kr, const s16x8* vr) {
#pragma unroll
            for (int i = 0; i < 4; ++i) {
                int ch = tid + i * 256;
                *(s16x8*)&lsK[(ch >> 3) * 72 + (ch & 7) * 8] = kr[i];
            }
#pragma unroll
            for (int i = 0; i < 4; ++i) {
                int ch = tid + i * 256;
                *(s16x8*)&lsV[(ch >> 4) * 136 + (ch & 15) * 8] = vr[i];
            }
        };

        auto tile = [&](auto CC, int kv0, s16x8* kc, s16x8* vc,
                        s16x8* kn, s16x8* vn, int kvn) {
            constexpr bool CAUS = decltype(CC)::value;

            lds_barrier();                 // prev tile's LDS reads (P, V) complete everywhere
            stage_write(kc, vc);
            if (kvn >= 0) issue(kvn, kn, vn);   // prefetch: survives the raw barriers below

            float madd[8];
#pragma unroll
            for (int nt = 0; nt < 8; ++nt)
                madd[nt] = (mask[b * SS + kv0 + nt * 16 + l15] != 0) ? 0.f : -1e30f;

            lds_barrier();                 // staging visible to all waves (vmcnt NOT drained)

            // S = Q K^T
            f32x4 sv[8];
#pragma unroll
            for (int nt = 0; nt < 8; ++nt) sv[nt] = f32x4{};
#pragma unroll
            for (int ks = 0; ks < 2; ++ks)
#pragma unroll
                for (int nt = 0; nt < 8; ++nt) {
                    s16x8 kf = *(const s16x8*)&lsK[(nt * 16 + l15) * 72 + ks * 32 + quad * 8];
                    sv[nt] = __builtin_amdgcn_mfma_f32_16x16x32_bf16(aq[ks], kf, sv[nt], 0, 0, 0);
                }

#pragma unroll
            for (int nt = 0; nt < 8; ++nt) {
                int colg = kv0 + nt * 16 + l15;
#pragma unroll
                for (int r = 0; r < 4; ++r) {
                    float scv = sv[nt][r] * SC + madd[nt];
                    if (CAUS && colg > rowg0 + r) scv = -1e30f;
                    sv[nt][r] = scv;
                }
            }
            // online softmax (rows in 16-lane groups)
            float alpha[4];
#pragma unroll
            for (int r = 0; r < 4; ++r) {
                float rm = sv[0][r];
#pragma unroll
                for (int nt = 1; nt < 8; ++nt) rm = fmaxf(rm, sv[nt][r]);
                rm = fmaxf(rm, __shfl_xor(rm, 1));
                rm = fmaxf(rm, __shfl_xor(rm, 2));
                rm = fmaxf(rm, __shfl_xor(rm, 4));
                rm = fmaxf(rm, __shfl_xor(rm, 8));
                float nm = fmaxf(m_r[r], rm);
                alpha[r] = __builtin_amdgcn_exp2f(m_r[r] - nm);
                m_r[r] = nm;
                float rs = 0.f;
#pragma unroll
                for (int nt = 0; nt < 8; ++nt) {
                    float p = __builtin_amdgcn_exp2f(sv[nt][r] - nm);
                    sv[nt][r] = p;
                    rs += p;
                }
                rs += __shfl_xor(rs, 1);
                rs += __shfl_xor(rs, 2);
                rs += __shfl_xor(rs, 4);
                rs += __shfl_xor(rs, 8);
                l_r[r] = l_r[r] * alpha[r] + rs;
            }
#pragma unroll
            for (int ht = 0; ht < 4; ++ht)
#pragma unroll
                for (int r = 0; r < 4; ++r)
                    o_acc[ht][r] *= alpha[r];

            lds_barrier();                 // all waves done reading lsK as K -> safe to write P

            // P -> per-wave swizzled region (aliases lsK)
#pragma unroll
            for (int nt = 0; nt < 8; ++nt)
#pragma unroll
                for (int r = 0; r < 4; ++r)
                    lsPw[((quad * 4 + r) * 136 + nt * 16 + l15) ^ wsw] = f2bf(sv[nt][r]);
            asm volatile("s_waitcnt lgkmcnt(0)" ::: "memory");
            __builtin_amdgcn_sched_barrier(0);

            // O += P V
            s16x8 ap[4];
#pragma unroll
            for (int k2 = 0; k2 < 4; ++k2)
                ap[k2] = *(const s16x8*)&lsPw[(l15 * 136 + k2 * 32 + quad * 8) ^ rsw];
#pragma unroll
            for (int ht = 0; ht < 4; ++ht)
#pragma unroll
                for (int k2 = 0; k2 < 4; ++k2) {
                    s16x8 vf = *(const s16x8*)&lsV[(ht * 16 + l15) * 136 + k2 * 32 + quad * 8];
                    o_acc[ht] = __builtin_amdgcn_mfma_f32_16x16x32_bf16(ap[k2], vf, o_acc[ht], 0, 0, 0);
                }
        };

        s16x8 kA[4], vA[4], kB[4], vB[4];
        const int ntiles = q0 / 128 + 1;   // uniform 128-key tiles, last is causal
        issue(0, kA, vA);
        for (int kt = 0; kt < ntiles; ++kt) {
            const int kvn = (kt + 1 < ntiles) ? (kt + 1) * 128 : -1;
            const bool lastt = (kt == ntiles - 1);
            if (!(kt & 1)) {
                if (lastt) tile(std::true_type{},  kt * 128, kA, vA, kB, vB, kvn);
                else       tile(std::false_type{}, kt * 128, kA, vA, kB, vB, kvn);
            } else {
                if (lastt) tile(std::true_type{},  kt * 128, kB, vB, kA, vA, kvn);
                else       tile(std::false_type{}, kt * 128, kB, vB, kA, vA, kvn);
            }
        }

        // epilogue: O/l -> (b, s, h*64+hd) bf16
        const int hcol = (bh & 15) * HDD;
#pragma unroll
        for (int r = 0; r < 4; ++r) {
            float inv = 1.0f / l_r[r];
            int srow = q0 + w * 16 + quad * 4 + r;
            size_t base = ((size_t)b * SS + srow) * DD + hcol;
#pragma unroll
            for (int ht = 0; ht < 4; ++ht)
                O[base + ht * 16 + l15] = f2bf(o_acc[ht][r] * inv);
        }
    }
}

// ---------------- launch ----------------
extern "C" void kernel_launch(void* const* d_in, const int* in_sizes, int n_in,
                              void* d_out, int out_size, void* d_ws, size_t ws_size,
                              hipStream_t stream) {
    const float* x     = (const float*)d_in[0];
    const int*   mask  = (const int*)d_in[1];
    const float* qkv_w = (const float*)d_in[2];
    const float* qkv_b = (const float*)d_in[3];
    const float* out_w = (const float*)d_in[4];
    const float* out_b = (const float*)d_in[5];
    float* out = (float*)d_out;

    const size_t M1 = (size_t)BB * SS;       // 8192
    short* ws  = (short*)d_ws;
    short* xb  = ws;
    short* qwb = xb  + M1 * DD;
    short* owb = qwb + (size_t)3 * DD * DD;
    short* Qb  = owb + (size_t)DD * DD;
    short* Kb  = Qb  + M1 * DD;
    short* Vb  = Kb  + M1 * DD;
    short* Ob  = Vb  + M1 * DD;

    cvt_kernel<<<(int)(M1 * DD / 8 / 256), 256, 0, stream>>>(x, xb, (int)(M1 * DD));
    cvt_kernel<<<3 * DD * DD / 8 / 256, 256, 0, stream>>>(qkv_w, qwb, 3 * DD * DD);
    cvt_kernel<<<DD * DD / 8 / 256, 256, 0, stream>>>(out_w, owb, DD * DD);

    gemm_bt<1><<<dim3(64, 24), 256, 0, stream>>>(xb, qwb, qkv_b, nullptr,
                                                 Qb, Kb, Vb, 8192, 3072, 1024);
    attn_kernel<<<dim3(16, BB * HH), 256, 0, stream>>>(Qb, Kb, Vb, mask, Ob);
    gemm_bt<0><<<dim3(64, 8), 256, 0, stream>>>(Ob, owb, out_b, out,
                                                nullptr, nullptr, nullptr, 8192, 1024, 1024);
}

// Round 4
// 346.209 us; speedup vs baseline: 2.3615x; 2.3615x over previous
//
#include <hip/hip_runtime.h>
#include <stdint.h>
#include <type_traits>

// Problem constants
#define BB  4
#define SS  2048
#define DD  1024
#define HH  16
#define HDD 64

typedef __attribute__((ext_vector_type(8))) short s16x8;   // 8 bf16 (4 VGPRs)
typedef __attribute__((ext_vector_type(4))) float f32x4;   // MFMA C/D

__device__ inline short f2bf(float f) {
    union { float f; unsigned int u; } v; v.f = f;
    unsigned int r = (v.u + 0x7fffu + ((v.u >> 16) & 1u)) >> 16; // RNE
    return (short)r;
}

__device__ inline float bf2f(short s) {
    union { unsigned int u; float f; } v;
    v.u = ((unsigned int)(unsigned short)s) << 16;
    return v.f;
}

#define GLL(gp, lp) __builtin_amdgcn_global_load_lds( \
    (const __attribute__((address_space(1))) void*)(gp), \
    (__attribute__((address_space(3))) void*)(lp), 16, 0, 0)

// Raw barrier: orders this wave's LDS ops (lgkmcnt) then syncs. Does NOT
// drain vmcnt -> global_load_lds prefetch stays in flight across it.
__device__ inline void lds_barrier() {
    asm volatile("s_waitcnt lgkmcnt(0)" ::: "memory");
    __builtin_amdgcn_sched_barrier(0);
    __builtin_amdgcn_s_barrier();
    __builtin_amdgcn_sched_barrier(0);
}

// ---------------- fp32 -> bf16 cast (n % 8 == 0) ----------------
__global__ void cvt_kernel(const float* __restrict__ src, short* __restrict__ dst, int n) {
    int i = (blockIdx.x * 256 + threadIdx.x) * 8;
    if (i >= n) return;
    const float4* s = (const float4*)(src + i);
    float4 a = s[0], b = s[1];
    s16x8 o;
    o[0]=f2bf(a.x); o[1]=f2bf(a.y); o[2]=f2bf(a.z); o[3]=f2bf(a.w);
    o[4]=f2bf(b.x); o[5]=f2bf(b.y); o[6]=f2bf(b.z); o[7]=f2bf(b.w);
    *(s16x8*)(dst + i) = o;
}

// ---------------- GEMM C = A @ B^T + bias (m97 structure) ----------------
template<int EPI>
__global__ __launch_bounds__(256)
void gemm_bt(const short* __restrict__ A, const short* __restrict__ Bw,
             const float* __restrict__ bias, float* __restrict__ Cf,
             short* __restrict__ Qo, short* __restrict__ Ko, short* __restrict__ Vo,
             int M, int N, int K)
{
    __shared__ short lsA[128 * 32];
    __shared__ short lsB[128 * 32];
    const int tid  = threadIdx.x;
    const int w    = tid >> 6, lane = tid & 63;
    const int quad = lane >> 4, l15 = lane & 15;
    const int m0 = blockIdx.x * 128, n0 = blockIdx.y * 128;
    const int mw = (w & 1) * 64, nw = (w >> 1) * 64;

    f32x4 acc[4][4] = {};

    const int srow = w * 32 + (lane >> 2);
    const int scol = (lane & 3) * 8;
    const short* pA = A + (size_t)(m0 + srow) * K + scol;
    const short* pB = Bw + (size_t)(n0 + srow) * K + scol;
    short* lAbase0 = &lsA[(w * 32) * 32];
    short* lAbase1 = &lsA[(w * 32 + 16) * 32];
    short* lBbase0 = &lsB[(w * 32) * 32];
    short* lBbase1 = &lsB[(w * 32 + 16) * 32];

    for (int kk = 0; kk < K; kk += 32) {
        __syncthreads();
        GLL(pA + kk,            lAbase0);
        GLL(pA + kk + 16 * K,   lAbase1);
        GLL(pB + kk,            lBbase0);
        GLL(pB + kk + 16 * K,   lBbase1);
        asm volatile("s_waitcnt vmcnt(0)" ::: "memory");
        __syncthreads();

        s16x8 af[4], bfr[4];
        for (int t = 0; t < 4; ++t) {
            af[t]  = *(const s16x8*)&lsA[(mw + t * 16 + l15) * 32 + quad * 8];
            bfr[t] = *(const s16x8*)&lsB[(nw + t * 16 + l15) * 32 + quad * 8];
        }
        for (int i = 0; i < 4; ++i)
            for (int j = 0; j < 4; ++j)
                acc[i][j] = __builtin_amdgcn_mfma_f32_16x16x32_bf16(af[i], bfr[j], acc[i][j], 0, 0, 0);
    }

    if (EPI == 0) {
        for (int i = 0; i < 4; ++i) {
            int row = m0 + mw + i * 16 + quad * 4;
            for (int j = 0; j < 4; ++j) {
                int col = n0 + nw + j * 16 + l15;
                float bv = bias[col];
                for (int r = 0; r < 4; ++r)
                    Cf[(size_t)(row + r) * N + col] = acc[i][j][r] + bv;
            }
        }
    } else {
        for (int i = 0; i < 4; ++i) {
            int row = m0 + mw + i * 16 + quad * 4;
            for (int j = 0; j < 4; ++j) {
                int col = n0 + nw + j * 16 + l15;
                float bv = bias[col];
                int sel = col >> 10, h = (col >> 6) & 15, hd = col & 63;
                for (int r = 0; r < 4; ++r) {
                    int rr = row + r;
                    int b = rr >> 11, s = rr & 2047;
                    short val = f2bf(acc[i][j][r] + bv);
                    if (sel == 0)      Qo[(((size_t)b * HH + h) * SS + s) * HDD + hd] = val;
                    else if (sel == 1) Ko[(((size_t)b * HH + h) * SS + s) * HDD + hd] = val;
                    else               Vo[(((size_t)b * HH + h) * HDD + hd) * SS + s] = val;
                }
            }
        }
    }
}

// ---------------- causal flash attention (GLL prefetch + counted vmcnt) ----------------
// Q,K: (b,h,s,hd) bf16; V: (b,h,hd,s) bf16; O: (b,s,h*64+hd) bf16
// grid: (16, B*H). Block t-loop: q-tiles {31-bx, bx} -> exactly 33 key-tiles/block.
// KVBLK=64. K,V double-buffered; staged via global_load_lds (NO reg staging, no VGPR
// cost, rule #20 safe). GLL needs linear LDS dest (m104) -> rule #21: pre-swizzle the
// per-lane GLOBAL source (granule c8 -> c8^(row&7)) + same XOR on ds_read. Per tile:
//   barrier A (release buf^1) -> issue 4 GLL for kt+1 into buf^1 ->
//   s_waitcnt vmcnt(4) (kt's GLLs done; kt+1's stay IN FLIGHT) -> barrier B ->
//   QK^T / softmax / P(swizzled, per-wave) / PV  from buf.
// No vmcnt(0) in the steady loop (T4). Mask pre-staged to LDS once (keeps vmcnt
// accounting pure-GLL). LDS 54272 B -> 3 blocks/CU.
__global__ __launch_bounds__(256, 3)
void attn_kernel(const short* __restrict__ Q, const short* __restrict__ Kb,
                 const short* __restrict__ Vb, const int* __restrict__ mask,
                 short* __restrict__ O)
{
    __shared__ short lsK[2][64 * 64];      // [buf][key][hd] linear (GLL), src-swizzled
    __shared__ short lsV[2][64 * 64];      // [buf][hd][key] linear (GLL), src-swizzled
    __shared__ short lsP[4][16 * 136];     // per-wave P, verified wsw/rsw XOR layout
    __shared__ short lsM[SS];              // mask additive, bf16 (0 or -1e30)

    const int tid  = threadIdx.x;
    const int w    = tid >> 6, lane = tid & 63;
    const int quad = lane >> 4, l15 = lane & 15;
    const int bx = blockIdx.x, bh = blockIdx.y;
    const int b = bh >> 4;
    const size_t baseQK = (size_t)bh * SS * HDD;
    const size_t baseV  = (size_t)bh * HDD * SS;
    short* lsPw = lsP[w];
    const float SC = 0.18033688f;          // (1/8) * log2(e)
    const int rsw = (l15 >> 3) << 4;       // P read-side XOR (shorts)
    const int wsw = (quad >> 1) << 4;      // P write-side XOR
    const int grow = lane >> 3;            // GLL: row-within-8 covered by this lane
    const int gcol = ((lane & 7) ^ grow) * 8;  // GLL: inverse-swizzled source col (shorts)
    const int l7 = l15 & 7;

    // stage mask -> lsM once (visible after first lds_barrier)
    {
        const int4* mp = (const int4*)(mask + b * SS);
        int4 a = mp[tid * 2], c = mp[tid * 2 + 1];
        const short NEG = f2bf(-1e30f);
        s16x8 mo;
        mo[0] = a.x ? (short)0 : NEG; mo[1] = a.y ? (short)0 : NEG;
        mo[2] = a.z ? (short)0 : NEG; mo[3] = a.w ? (short)0 : NEG;
        mo[4] = c.x ? (short)0 : NEG; mo[5] = c.y ? (short)0 : NEG;
        mo[6] = c.z ? (short)0 : NEG; mo[7] = c.w ? (short)0 : NEG;
        *(s16x8*)&lsM[tid * 8] = mo;
    }

    // issue tile (kv0) K/V global->LDS DMA into buffer buf: 4 GLL per wave
    auto issue = [&](int kv0, int buf) {
#pragma unroll
        for (int jj = 0; jj < 2; ++jj) {
            int row = w * 16 + jj * 8 + grow;                  // key row
            GLL(Kb + baseQK + (size_t)(kv0 + row) * HDD + gcol,
                &lsK[buf][(w * 2 + jj) * 512]);
        }
#pragma unroll
        for (int jj = 0; jj < 2; ++jj) {
            int row = w * 16 + jj * 8 + grow;                  // hd row
            GLL(Vb + baseV + (size_t)row * SS + kv0 + gcol,
                &lsV[buf][(w * 2 + jj) * 512]);
        }
    };

    for (int t = 0; t < 2; ++t) {
        const int qb = t ? bx : (31 - bx);  // heavy tile first
        const int q0 = qb * 64;
        const int qrow = q0 + w * 16 + l15;
        const int rowg0 = q0 + w * 16 + quad * 4;

        s16x8 aq[2];
#pragma unroll
        for (int ks = 0; ks < 2; ++ks)
            aq[ks] = *(const s16x8*)(Q + baseQK + (size_t)qrow * HDD + ks * 32 + quad * 8);

        float m_r[4], l_r[4];
        f32x4 o_acc[4] = {};
#pragma unroll
        for (int r = 0; r < 4; ++r) { m_r[r] = -1e30f; l_r[r] = 0.f; }

        const int ntiles = qb + 1;          // 64-key tiles; last is the diagonal (causal)

        lds_barrier();                      // prev t's reads done / mask visible
        issue(0, 0);

        auto tile = [&](auto CC, int kv0, int buf, int kvn) {
            constexpr bool CAUS = decltype(CC)::value;

            lds_barrier();                  // A: all waves done reading buf^1 last tile
            if (kvn >= 0) issue(kvn, buf ^ 1);

            float madd[4];
#pragma unroll
            for (int nt = 0; nt < 4; ++nt)
                madd[nt] = bf2f(lsM[kv0 + nt * 16 + l15]);

            if (kvn >= 0) asm volatile("s_waitcnt vmcnt(4)" ::: "memory");
            else          asm volatile("s_waitcnt vmcnt(0)" ::: "memory");
            __builtin_amdgcn_sched_barrier(0);
            __builtin_amdgcn_s_barrier();   // B: all waves' GLLs for buf landed
            __builtin_amdgcn_sched_barrier(0);

            // S = Q K^T (swizzled K reads)
            f32x4 sv[4];
#pragma unroll
            for (int nt = 0; nt < 4; ++nt) sv[nt] = f32x4{};
#pragma unroll
            for (int ks = 0; ks < 2; ++ks)
#pragma unroll
                for (int nt = 0; nt < 4; ++nt) {
                    s16x8 kf = *(const s16x8*)&lsK[buf][(nt * 16 + l15) * 64 +
                                                       (((ks * 4 + quad) ^ l7) * 8)];
                    sv[nt] = __builtin_amdgcn_mfma_f32_16x16x32_bf16(aq[ks], kf, sv[nt], 0, 0, 0);
                }

#pragma unroll
            for (int nt = 0; nt < 4; ++nt) {
                int colg = kv0 + nt * 16 + l15;
#pragma unroll
                for (int r = 0; r < 4; ++r) {
                    float scv = sv[nt][r] * SC + madd[nt];
                    if (CAUS && colg > rowg0 + r) scv = -1e30f;
                    sv[nt][r] = scv;
                }
            }
            // online softmax (rows in 16-lane groups)
            float alpha[4];
#pragma unroll
            for (int r = 0; r < 4; ++r) {
                float rm = fmaxf(fmaxf(sv[0][r], sv[1][r]), fmaxf(sv[2][r], sv[3][r]));
                rm = fmaxf(rm, __shfl_xor(rm, 1));
                rm = fmaxf(rm, __shfl_xor(rm, 2));
                rm = fmaxf(rm, __shfl_xor(rm, 4));
                rm = fmaxf(rm, __shfl_xor(rm, 8));
                float nm = fmaxf(m_r[r], rm);
                alpha[r] = __builtin_amdgcn_exp2f(m_r[r] - nm);
                m_r[r] = nm;
                float rs = 0.f;
#pragma unroll
                for (int nt = 0; nt < 4; ++nt) {
                    float p = __builtin_amdgcn_exp2f(sv[nt][r] - nm);
                    sv[nt][r] = p;
                    rs += p;
                }
                rs += __shfl_xor(rs, 1);
                rs += __shfl_xor(rs, 2);
                rs += __shfl_xor(rs, 4);
                rs += __shfl_xor(rs, 8);
                l_r[r] = l_r[r] * alpha[r] + rs;
            }
#pragma unroll
            for (int ht = 0; ht < 4; ++ht)
#pragma unroll
                for (int r = 0; r < 4; ++r)
                    o_acc[ht][r] *= alpha[r];

            // P -> per-wave swizzled region (wave-private: lgkmcnt-only sync)
#pragma unroll
            for (int nt = 0; nt < 4; ++nt)
#pragma unroll
                for (int r = 0; r < 4; ++r)
                    lsPw[((quad * 4 + r) * 136 + nt * 16 + l15) ^ wsw] = f2bf(sv[nt][r]);
            asm volatile("s_waitcnt lgkmcnt(0)" ::: "memory");
            __builtin_amdgcn_sched_barrier(0);

            // O += P V (swizzled V reads)
            s16x8 ap[2];
#pragma unroll
            for (int k2 = 0; k2 < 2; ++k2)
                ap[k2] = *(const s16x8*)&lsPw[(l15 * 136 + k2 * 32 + quad * 8) ^ rsw];
#pragma unroll
            for (int ht = 0; ht < 4; ++ht)
#pragma unroll
                for (int k2 = 0; k2 < 2; ++k2) {
                    s16x8 vf = *(const s16x8*)&lsV[buf][(ht * 16 + l15) * 64 +
                                                        (((k2 * 4 + quad) ^ l7) * 8)];
                    o_acc[ht] = __builtin_amdgcn_mfma_f32_16x16x32_bf16(ap[k2], vf, o_acc[ht], 0, 0, 0);
                }
        };

        for (int kt = 0; kt < ntiles; ++kt) {
            const int kvn = (kt + 1 < ntiles) ? (kt + 1) * 64 : -1;
            if (kt == ntiles - 1) tile(std::true_type{},  kt * 64, kt & 1, kvn);
            else                  tile(std::false_type{}, kt * 64, kt & 1, kvn);
        }

        // epilogue: O/l -> (b, s, h*64+hd) bf16
        const int hcol = (bh & 15) * HDD;
#pragma unroll
        for (int r = 0; r < 4; ++r) {
            float inv = 1.0f / l_r[r];
            int srow = q0 + w * 16 + quad * 4 + r;
            size_t base = ((size_t)b * SS + srow) * DD + hcol;
#pragma unroll
            for (int ht = 0; ht < 4; ++ht)
                O[base + ht * 16 + l15] = f2bf(o_acc[ht][r] * inv);
        }
    }
}

// ---------------- launch ----------------
extern "C" void kernel_launch(void* const* d_in, const int* in_sizes, int n_in,
                              void* d_out, int out_size, void* d_ws, size_t ws_size,
                              hipStream_t stream) {
    const float* x     = (const float*)d_in[0];
    const int*   mask  = (const int*)d_in[1];
    const float* qkv_w = (const float*)d_in[2];
    const float* qkv_b = (const float*)d_in[3];
    const float* out_w = (const float*)d_in[4];
    const float* out_b = (const float*)d_in[5];
    float* out = (float*)d_out;

    const size_t M1 = (size_t)BB * SS;       // 8192
    short* ws  = (short*)d_ws;
    short* xb  = ws;
    short* qwb = xb  + M1 * DD;
    short* owb = qwb + (size_t)3 * DD * DD;
    short* Qb  = owb + (size_t)DD * DD;
    short* Kb  = Qb  + M1 * DD;
    short* Vb  = Kb  + M1 * DD;
    short* Ob  = Vb  + M1 * DD;

    cvt_kernel<<<(int)(M1 * DD / 8 / 256), 256, 0, stream>>>(x, xb, (int)(M1 * DD));
    cvt_kernel<<<3 * DD * DD / 8 / 256, 256, 0, stream>>>(qkv_w, qwb, 3 * DD * DD);
    cvt_kernel<<<DD * DD / 8 / 256, 256, 0, stream>>>(out_w, owb, DD * DD);

    gemm_bt<1><<<dim3(64, 24), 256, 0, stream>>>(xb, qwb, qkv_b, nullptr,
                                                 Qb, Kb, Vb, 8192, 3072, 1024);
    attn_kernel<<<dim3(16, BB * HH), 256, 0, stream>>>(Qb, Kb, Vb, mask, Ob);
    gemm_bt<0><<<dim3(64, 8), 256, 0, stream>>>(Ob, owb, out_b, out,
                                                nullptr, nullptr, nullptr, 8192, 1024, 1024);
}